// Round 1
// baseline (33.361 us; speedup 1.0000x reference)
//
#include <hip/hip_runtime.h>
#include <hip/hip_bf16.h>

// Householder reflection: out[r] = z[r] - 2 * v[r] * (v[r].z[r]) / ||v[r]||^2
// B = 8192 rows, L = 2048 cols, fp32. Memory-bound: 192 MiB total traffic.
// One 256-thread block per row; row data held in registers between the
// dot-product pass and the output pass (no re-read from HBM/L2).

#define L_DIM 2048
#define BLOCK 256

__global__ __launch_bounds__(BLOCK) void householder_kernel(
    const float* __restrict__ v,
    const float* __restrict__ z,
    float* __restrict__ out)
{
    const size_t row_off = (size_t)blockIdx.x * L_DIM;
    const float4* __restrict__ v4 = reinterpret_cast<const float4*>(v + row_off);
    const float4* __restrict__ z4 = reinterpret_cast<const float4*>(z + row_off);
    float4* __restrict__ o4 = reinterpret_cast<float4*>(out + row_off);

    const int t = threadIdx.x;

    // L/4 = 512 float4 per row, 256 threads -> 2 float4 of v and z each.
    float4 va = v4[t];
    float4 vb = v4[t + BLOCK];
    float4 za = z4[t];
    float4 zb = z4[t + BLOCK];

    float vz = va.x * za.x + va.y * za.y + va.z * za.z + va.w * za.w
             + vb.x * zb.x + vb.y * zb.y + vb.z * zb.z + vb.w * zb.w;
    float vv = va.x * va.x + va.y * va.y + va.z * va.z + va.w * va.w
             + vb.x * vb.x + vb.y * vb.y + vb.z * vb.z + vb.w * vb.w;

    // Wave-level butterfly reduction (64 lanes).
    #pragma unroll
    for (int off = 32; off > 0; off >>= 1) {
        vz += __shfl_xor(vz, off);
        vv += __shfl_xor(vv, off);
    }

    // Combine the 4 waves via LDS.
    __shared__ float s_vz[BLOCK / 64];
    __shared__ float s_vv[BLOCK / 64];
    const int wave = t >> 6;
    if ((t & 63) == 0) {
        s_vz[wave] = vz;
        s_vv[wave] = vv;
    }
    __syncthreads();

    vz = s_vz[0] + s_vz[1] + s_vz[2] + s_vz[3];
    vv = s_vv[0] + s_vv[1] + s_vv[2] + s_vv[3];

    const float scale = 2.0f * vz / vv;

    float4 oa, ob;
    oa.x = za.x - scale * va.x;
    oa.y = za.y - scale * va.y;
    oa.z = za.z - scale * va.z;
    oa.w = za.w - scale * va.w;
    ob.x = zb.x - scale * vb.x;
    ob.y = zb.y - scale * vb.y;
    ob.z = zb.z - scale * vb.z;
    ob.w = zb.w - scale * vb.w;

    o4[t] = oa;
    o4[t + BLOCK] = ob;
}

extern "C" void kernel_launch(void* const* d_in, const int* in_sizes, int n_in,
                              void* d_out, int out_size, void* d_ws, size_t ws_size,
                              hipStream_t stream) {
    const float* v = (const float*)d_in[0];
    const float* z = (const float*)d_in[1];
    float* out = (float*)d_out;

    const int B = in_sizes[0] / L_DIM;  // 8192
    householder_kernel<<<B, BLOCK, 0, stream>>>(v, z, out);
}